// Round 6
// baseline (87.946 us; speedup 1.0000x reference)
//
#include <hip/hip_runtime.h>

typedef unsigned short u16;
typedef unsigned int u32;
typedef __attribute__((ext_vector_type(8))) short bf16x8;
typedef __attribute__((ext_vector_type(4))) float f32x4;
typedef __attribute__((ext_vector_type(4))) unsigned short u16x4;

#define DEVI __device__ __forceinline__

constexpr float L2GAMMA = -0.15200309344504997f; // log2(0.9)
constexpr float INV_SQRT_H = 0.0625f;            // 1/sqrt(256)

DEVI u16 f2bf(float x) {
  union { float f; unsigned u; } v; v.f = x;
  unsigned r = v.u + 0x7FFFu + ((v.u >> 16) & 1u);
  return (u16)(r >> 16);
}

// pack two floats -> two bf16 (round-half-up) in one u32 via v_perm
DEVI u32 pack2bf(float f0, float f1) {
  u32 u0 = __float_as_uint(f0) + 0x8000u;
  u32 u1 = __float_as_uint(f1) + 0x8000u;
  return __builtin_amdgcn_perm(u1, u0, 0x07060302u); // [f1.hi16 : f0.hi16]
}

// ---- kernel 0: W_Q|W_K|W_V (each 256x1024 fp32) -> Wb[768][1024] bf16 ----
__global__ void cvt_w_kernel(const float4* __restrict__ wq, const float4* __restrict__ wk,
                             const float4* __restrict__ wv, u16x4* __restrict__ dst) {
  int i = blockIdx.x * blockDim.x + threadIdx.x; // 0..196607 (grid exactly covers)
  int w = i >> 16, off = i & 65535;
  const float4* s = (w == 0) ? wq : ((w == 1) ? wk : wv);
  float4 v = s[off];
  u16x4 o; o.x = f2bf(v.x); o.y = f2bf(v.y); o.z = f2bf(v.z); o.w = f2bf(v.w);
  dst[(w << 16) + off] = o;
}

// ---- kernel 1: fused QKV GEMM  C[16384x768] = x[16384x1024](fp32)*Wb^T ---
// BM=BN=256, BK=32, 512 thr (8 waves, 2Mx4N; wave out 128x64).
// Grid 192 = 64 m-panels x 3 n-tiles; XCD-chunked: each XCD owns 8 m-panels
// (A-panel shared by its 3 n-WGs via L2).
// 4-buffer LDS rotation (128 KB): tile t reads buf t&3, stages t+2 into
// buf (t+2)&3 -> never overlaps any readable buffer (race-free).
// Counted vmcnt(6) at tile end (never 0 until tail): A-regs(t+2)+B(t+1)
// confirmed, B(t+2)/A(t+4) stay in flight across the raw s_barrier.
// A fused fp32->bf16: 2-generation reg staging (arE/arO), cvt+ds_write.
// Swizzle: 16B slots, phys col = col ^ ((row>>2)&3) (involution); readers
// hit all 8 bank-quads 2-way (free); staging writes are slot-linear.
__global__ __launch_bounds__(512, 2) void qkv_gemm_kernel(const float* __restrict__ Xf, const u16* __restrict__ Wb,
                                                          u16* __restrict__ Qb, u16* __restrict__ Kb,
                                                          u16* __restrict__ Vt) {
  __shared__ u16 lds[4][16384];   // per buf: A = [0..8191], B = [8192..16383]
  const int raw = blockIdx.x;     // 0..191
  const int xcd = raw & 7, idx = raw >> 3;   // idx 0..23
  const int m0 = (xcd * 8 + idx / 3) * 256;
  const int nt = idx % 3;
  const int n0 = nt * 256;
  const int tid = threadIdx.x;
  const int wid = tid >> 6, lane = tid & 63;
  const int wm = wid >> 2, wn = wid & 3;     // 2M x 4N
  const int lrow = lane & 15, lkg = lane >> 4;

#define STAGEB(T, BUF) do { const int k0_ = (T) * 32; \
  _Pragma("unroll") for (int i_ = 0; i_ < 2; ++i_) { \
    const int p_ = tid + i_ * 512; \
    const int row_ = p_ >> 2; \
    const int sc_ = ((p_ & 3) ^ ((p_ >> 4) & 3)) << 3; \
    const u16* g_ = Wb + (size_t)(n0 + row_) * 1024 + k0_ + sc_; \
    __builtin_amdgcn_global_load_lds((const __attribute__((address_space(1))) void*)g_, \
        (__attribute__((address_space(3))) void*)&lds[BUF][8192 + p_ * 8], 16, 0, 0); } } while (0)

#define LOADA(T, R) do { const int k0_ = (T) * 32; \
  _Pragma("unroll") for (int i_ = 0; i_ < 2; ++i_) { \
    const int p_ = tid + i_ * 512; \
    const int row_ = p_ >> 2; \
    const int sc_ = ((p_ & 3) ^ ((p_ >> 4) & 3)) << 3; \
    const float* g_ = Xf + (size_t)(m0 + row_) * 1024 + k0_ + sc_; \
    R[2 * i_]     = *(const float4*)g_; \
    R[2 * i_ + 1] = *(const float4*)(g_ + 4); } } while (0)

#define CVTWRITE(R, BUF) do { \
  _Pragma("unroll") for (int i_ = 0; i_ < 2; ++i_) { \
    const int p_ = tid + i_ * 512; \
    uint4 pk_; \
    pk_.x = pack2bf(R[2 * i_].x, R[2 * i_].y); \
    pk_.y = pack2bf(R[2 * i_].z, R[2 * i_].w); \
    pk_.z = pack2bf(R[2 * i_ + 1].x, R[2 * i_ + 1].y); \
    pk_.w = pack2bf(R[2 * i_ + 1].z, R[2 * i_ + 1].w); \
    *(uint4*)&lds[BUF][p_ * 8] = pk_; } } while (0)

  f32x4 acc[8][4] = {};
  float4 arE[4], arO[4];

  // ---- prologue: tiles 0,1 staged; arE=A(2), arO=A(3) in flight ----
  LOADA(0, arE); LOADA(1, arO);
  STAGEB(0, 0);  STAGEB(1, 1);
  CVTWRITE(arE, 0); LOADA(2, arE);
  CVTWRITE(arO, 1); LOADA(3, arO);
  asm volatile("s_waitcnt vmcnt(8)" ::: "memory");   // B(0),B(1) landed; A(2),A(3) in flight
  asm volatile("s_waitcnt lgkmcnt(0)" ::: "memory");
  __builtin_amdgcn_s_barrier();
  __builtin_amdgcn_sched_barrier(0);

#define BODY(T, AR) do { \
  const int t_ = (T); \
  const int rb_ = t_ & 3; \
  if (t_ + 2 < 32) STAGEB(t_ + 2, (t_ + 2) & 3); \
  bf16x8 af_[8], bf_[4]; \
  { const u16* Ab_ = &lds[rb_][0]; const u16* Bb_ = &lds[rb_][8192]; \
    const int sw_ = (lkg ^ ((lrow >> 2) & 3)) << 3; \
    _Pragma("unroll") for (int mf = 0; mf < 8; ++mf) \
      af_[mf] = *(const bf16x8*)&Ab_[(wm * 128 + mf * 16 + lrow) * 32 + sw_]; \
    _Pragma("unroll") for (int nf = 0; nf < 4; ++nf) \
      bf_[nf] = *(const bf16x8*)&Bb_[(wn * 64 + nf * 16 + lrow) * 32 + sw_]; } \
  __builtin_amdgcn_s_setprio(1); \
  _Pragma("unroll") for (int mf = 0; mf < 8; ++mf) \
    _Pragma("unroll") for (int nf = 0; nf < 4; ++nf) \
      acc[mf][nf] = __builtin_amdgcn_mfma_f32_16x16x32_bf16(af_[mf], bf_[nf], acc[mf][nf], 0, 0, 0); \
  __builtin_amdgcn_s_setprio(0); \
  if (t_ <= 28)      { asm volatile("s_waitcnt vmcnt(6)" ::: "memory"); } \
  else if (t_ == 29) { asm volatile("s_waitcnt vmcnt(2)" ::: "memory"); } \
  else               { asm volatile("s_waitcnt vmcnt(0)" ::: "memory"); } \
  if (t_ + 2 < 32) { CVTWRITE(AR, (t_ + 2) & 3); } \
  if (t_ + 4 < 32) { LOADA(t_ + 4, AR); } \
  asm volatile("s_waitcnt lgkmcnt(0)" ::: "memory"); \
  __builtin_amdgcn_s_barrier(); \
  __builtin_amdgcn_sched_barrier(0); \
} while (0)

  for (int ti = 0; ti < 16; ++ti) {
    BODY(2 * ti, arE);
    BODY(2 * ti + 1, arO);
  }

  // ---- epilogue: whole WG is one region (nt: 0=Q, 1=K, 2=V-transposed) ----
  if (nt < 2) {
    u16* Dst = (nt == 0) ? Qb : Kb;
#pragma unroll
    for (int mf = 0; mf < 8; ++mf)
#pragma unroll
      for (int nf = 0; nf < 4; ++nf) {
        const int gm = m0 + wm * 128 + mf * 16 + lkg * 4;
        const int c = wn * 64 + nf * 16 + lrow;
#pragma unroll
        for (int r = 0; r < 4; ++r) Dst[(size_t)(gm + r) * 256 + c] = f2bf(acc[mf][nf][r]);
      }
  } else {
#pragma unroll
    for (int mf = 0; mf < 8; ++mf)
#pragma unroll
      for (int nf = 0; nf < 4; ++nf) {
        const int gm = m0 + wm * 128 + mf * 16 + lkg * 4;
        const int h = wn * 64 + nf * 16 + lrow;
        const int bb = gm >> 12, l = gm & 4095;
        u16x4 pk;
        pk.x = f2bf(acc[mf][nf][0]); pk.y = f2bf(acc[mf][nf][1]);
        pk.z = f2bf(acc[mf][nf][2]); pk.w = f2bf(acc[mf][nf][3]);
        *(u16x4*)&Vt[((size_t)bb * 256 + h) * 4096 + l] = pk;
      }
  }
}

// ---- kernel 2: WINDOWED decay attention ----------------------------------
// gamma^320 ~ 2.5e-15 => keys older than the aligned 256..319 window are
// numerically zero in fp32. QB=32 rows/WG, KB=64, 4 waves (256 thr).
__global__ __launch_bounds__(256) void attn_kernel(const u16* __restrict__ Qb, const u16* __restrict__ Kb,
                                                   const u16* __restrict__ Vt, float* __restrict__ out) {
  __shared__ u16 Plds[32 * 72];
  const int raw = blockIdx.x;                 // 0..511
  const int aid = (raw & 7) * 64 + (raw >> 3);  // XCD-chunked
  const int b = aid >> 7;                     // 0..3
  const int qt = aid & 127;                   // 0..127
  const int qb = qt * 32;
  const int tid = threadIdx.x;
  const int wid = tid >> 6, lane = tid & 63;
  const int lrow = lane & 15, lkg = lane >> 4, lk = lkg * 8;
  const size_t bQK = (size_t)b * 4096 * 256;

  bf16x8 qf[2][8];
#pragma unroll
  for (int mf = 0; mf < 2; ++mf) {
    const u16* Qrow = Qb + bQK + (size_t)(qb + mf * 16 + lrow) * 256;
#pragma unroll
    for (int kf = 0; kf < 8; ++kf) qf[mf][kf] = *(const bf16x8*)&Qrow[kf * 32 + lk];
  }

  int kstart = qb - 256; if (kstart < 0) kstart = 0; kstart &= ~63;
  const int njt = (qb + 32 - kstart + 63) >> 6;

  f32x4 oacc[2][4] = {};

  for (int jt = 0; jt < njt; ++jt) {
    const int kb = kstart + jt * 64;
    f32x4 s[2] = {};
    const u16* Krow = Kb + bQK + (size_t)(kb + wid * 16 + lrow) * 256;
#pragma unroll
    for (int kf = 0; kf < 8; ++kf) {
      const bf16x8 kfr = *(const bf16x8*)&Krow[kf * 32 + lk];
      s[0] = __builtin_amdgcn_mfma_f32_16x16x32_bf16(qf[0][kf], kfr, s[0], 0, 0, 0);
      s[1] = __builtin_amdgcn_mfma_f32_16x16x32_bf16(qf[1][kf], kfr, s[1], 0, 0, 0);
    }
    const int kg = kb + wid * 16 + lrow;
#pragma unroll
    for (int mf = 0; mf < 2; ++mf) {
      const int qg = qb + mf * 16 + lkg * 4;
#pragma unroll
      for (int r = 0; r < 4; ++r) {
        const int d = qg + r - kg;
        const float pv = (d >= 0) ? s[mf][r] * exp2f((float)d * L2GAMMA) * INV_SQRT_H : 0.0f;
        Plds[(mf * 16 + lkg * 4 + r) * 72 + wid * 16 + lrow] = f2bf(pv);
      }
    }
    __syncthreads();
#pragma unroll
    for (int ks = 0; ks < 2; ++ks) {
      bf16x8 pa[2];
      pa[0] = *(const bf16x8*)&Plds[(lrow) * 72 + ks * 32 + lk];
      pa[1] = *(const bf16x8*)&Plds[(16 + lrow) * 72 + ks * 32 + lk];
#pragma unroll
      for (int nf = 0; nf < 4; ++nf) {
        const bf16x8 vb = *(const bf16x8*)&Vt[((size_t)b * 256 + wid * 64 + nf * 16 + lrow) * 4096 + kb + ks * 32 + lk];
        oacc[0][nf] = __builtin_amdgcn_mfma_f32_16x16x32_bf16(pa[0], vb, oacc[0][nf], 0, 0, 0);
        oacc[1][nf] = __builtin_amdgcn_mfma_f32_16x16x32_bf16(pa[1], vb, oacc[1][nf], 0, 0, 0);
      }
    }
    __syncthreads();
  }

#pragma unroll
  for (int mf = 0; mf < 2; ++mf) {
    float* obase = out + ((size_t)b * 4096 + qb + mf * 16 + lkg * 4) * 256 + wid * 64 + lrow;
#pragma unroll
    for (int nf = 0; nf < 4; ++nf)
#pragma unroll
      for (int r = 0; r < 4; ++r)
        obase[(size_t)r * 256 + nf * 16] = oacc[mf][nf][r];
  }
}

extern "C" void kernel_launch(void* const* d_in, const int* in_sizes, int n_in,
                              void* d_out, int out_size, void* d_ws, size_t ws_size,
                              hipStream_t stream) {
  const float* x  = (const float*)d_in[0];
  const float* wq = (const float*)d_in[1];
  const float* wk = (const float*)d_in[2];
  const float* wv = (const float*)d_in[3];
  float* out = (float*)d_out;
  char* ws = (char*)d_ws;
  u16* Wb = (u16*)(ws);                          //   768*1024*2 = 1,572,864
  u16* Qb = (u16*)(ws + (size_t)1572864);        // 16384*256*2  = 8,388,608
  u16* Kb = (u16*)(ws + (size_t)9961472);        //  8,388,608
  u16* Vt = (u16*)(ws + (size_t)18350080);       //  8,388,608  (end 26,738,688)

  hipLaunchKernelGGL(cvt_w_kernel, dim3(768), dim3(256), 0, stream,
                     (const float4*)wq, (const float4*)wk, (const float4*)wv, (u16x4*)Wb);
  hipLaunchKernelGGL(qkv_gemm_kernel, dim3(192), dim3(512), 0, stream, x, Wb, Qb, Kb, Vt);
  hipLaunchKernelGGL(attn_kernel, dim3(512), dim3(256), 0, stream, Qb, Kb, Vt, out);
}